// Round 20
// baseline (577.039 us; speedup 1.0000x reference)
//
#include <hip/hip_runtime.h>
#include <hip/hip_bf16.h>

typedef unsigned short u16;
typedef unsigned int   u32;
typedef short bf16x8 __attribute__((ext_vector_type(8)));
typedef float f32x4  __attribute__((ext_vector_type(4)));

#define DEV static __device__ __forceinline__

#define Bc 8
#define Lc 1024
#define Hc 1024
#define Ec 8
#define Ic 256
#define ISc 512
#define NHc 4
#define HDc 256
#define NTOK 8192
#define EPSc 1e-6f
#define MAXSLOTS 17408

DEV u16 f2bf(float f){
  u32 u = __float_as_uint(f);
  return (u16)((u + 0x7fffu + ((u >> 16) & 1u)) >> 16);
}
DEV float bf2f(u16 h){ return __uint_as_float(((u32)h) << 16); }

DEV void gload_lds16(const void* g, void* l){
  __builtin_amdgcn_global_load_lds((const __attribute__((address_space(1))) u32*)g,
                                   (__attribute__((address_space(3))) u32*)l, 16, 0, 0);
}

// compact live m-block remap: slot in [0,64) -> live block i = (slot&7)+8*(slot>>3)
DEV bool compact_m0(const int* __restrict__ tc, int slot, int& m0){
  int cb[8], Lt = 0;
#pragma unroll
  for (int b = 0; b < 8; b++){ cb[b] = (tc[b] + 127) >> 7; Lt += cb[b]; }
  const int i = (slot & 7) + 8*(slot >> 3);
  if (i >= Lt) return false;
  int acc = 0, bsel = 0, pos = 0;
#pragma unroll
  for (int b = 0; b < 8; b++){
    if (i < acc + cb[b]){ bsel = b; pos = i - acc; break; }
    acc += cb[b];
  }
  m0 = (bsel*8 + pos)*128;
  return true;
}

// ---------------------------------------------------------------------------
// Split-precision NT GEMM: 4-plane LDS double-buffer (round-14 optimum),
// 512 thr / 8 waves (4x2), wave tile 32x64 (acc[2][4]).
// EPI: 0 packed hi|lo (lo at +loOffC), 1 f32, 2 f32 acc+bias+Res,
//      3 V-transpose packed, 4 merged QKV
// SKIP: 0 none; 1 attn QK; 2 attn PV (K clamp); 3 pad-row; 4 compact-live
// SWZ: 0 (x=n,y=m); 1 slice->XCD; 2 transposed (x=m/slot)
// ZDEC: 0 zin=z&3; 1 zin=z&7
// ---------------------------------------------------------------------------
template<int EPI, int BIAS, int SKIP, int SWZ, int ZDEC>
__global__ __launch_bounds__(512)
void gemm3(const u16* __restrict__ Ahi, const u16* __restrict__ Alo,
           const u16* __restrict__ Bhi, const u16* __restrict__ Blo,
           void* __restrict__ Cv, const float* __restrict__ bias,
           const float* __restrict__ Res,
           int M, int N, int K, int lda, int ldb, int ldc,
           long sAin, long sAout, long sBin, long sBout, long sCin, long sCout,
           int loOffC, int biasStride, const int* __restrict__ tc, int bbase)
{
  __shared__ u16 lsAh[2][128*32];
  __shared__ u16 lsAl[2][128*32];
  __shared__ u16 lsBh[2][128*32];
  __shared__ u16 lsBl[2][128*32];
  int m_i, n_i, z;
  if (SWZ == 1){
    const int NB = gridDim.x*gridDim.y;
    const int L = blockIdx.x + gridDim.x*(blockIdx.y + gridDim.y*blockIdx.z);
    const int r = L & 7, k = L >> 3;
    z = r + 8*(k / NB);
    const int idx = k % NB;
    n_i = idx % gridDim.x; m_i = idx / gridDim.x;
  } else if (SWZ == 2){
    m_i = blockIdx.x; n_i = blockIdx.y; z = blockIdx.z;
  } else {
    n_i = blockIdx.x; m_i = blockIdx.y; z = blockIdx.z;
  }
  int n0 = n_i*128, m0 = m_i*128;
  const int zin  = ZDEC ? (z & 7)  : (z & 3);
  const int zout = ZDEC ? (z >> 3) : (z >> 2);
  if (SKIP == 1){ const int c = tc[bbase + zin]; if (m0 >= c || n0 >= c) return; }
  if (SKIP == 2){ const int c = tc[bbase + zin]; if (m0 >= c) return;
                  const int kl = (c + 31) & ~31; K = K < kl ? K : kl; }
  if (SKIP == 3){ if ((m0 & 1023) >= tc[m0 >> 10]) return; }
  if (SKIP == 4){ if (!compact_m0(tc, m_i, m0)) return; }
  const long aoff = (long)zin*sAin + (long)zout*sAout;
  const long boff = (long)zin*sBin + (long)zout*sBout;
  const long coff = (long)zin*sCin + (long)zout*sCout;
  const u16* Ahb = Ahi + aoff;
  const u16* Alb = Alo + aoff;
  const u16* Bhb = Bhi + boff;
  const u16* Blb = Blo + boff;
  const int t = threadIdx.x, lane = t & 63;
  const int w = t >> 6;                 // 8 waves
  const int wm = w >> 1, wn = w & 1;    // 4x2 wave grid: 32-row x 64-col tiles
  const int fr = lane & 15, kg = lane >> 4;
  const int srow = t >> 2, scol = (t & 3) * 8;   // 512 thr: 128 rows x 64B
  f32x4 acc[2][4] = {};

  auto stage = [&](int buf, int kb){
    gload_lds16(Ahb + (long)(m0 + srow)*lda + kb + scol, &lsAh[buf][srow*32 + scol]);
    gload_lds16(Alb + (long)(m0 + srow)*lda + kb + scol, &lsAl[buf][srow*32 + scol]);
    gload_lds16(Bhb + (long)(n0 + srow)*ldb + kb + scol, &lsBh[buf][srow*32 + scol]);
    gload_lds16(Blb + (long)(n0 + srow)*ldb + kb + scol, &lsBl[buf][srow*32 + scol]);
  };

  stage(0, 0);
  __syncthreads();              // implicit vmcnt(0): buf0 ready
  int cur = 0;
  for (int kb = 0; kb < K; kb += 32){
    if (kb + 32 < K) stage(cur ^ 1, kb + 32);   // prefetch next tile first
    bf16x8 ah[2], al[2], bh[4], bl[4];
#pragma unroll
    for (int i = 0; i < 2; i++){
      ah[i] = *(const bf16x8*)&lsAh[cur][(wm*32 + i*16 + fr)*32 + kg*8];
      al[i] = *(const bf16x8*)&lsAl[cur][(wm*32 + i*16 + fr)*32 + kg*8];
    }
#pragma unroll
    for (int j = 0; j < 4; j++){
      bh[j] = *(const bf16x8*)&lsBh[cur][(wn*64 + j*16 + fr)*32 + kg*8];
      bl[j] = *(const bf16x8*)&lsBl[cur][(wn*64 + j*16 + fr)*32 + kg*8];
    }
#pragma unroll
    for (int mi = 0; mi < 2; mi++)
#pragma unroll
      for (int ni = 0; ni < 4; ni++){
        acc[mi][ni] = __builtin_amdgcn_mfma_f32_16x16x32_bf16(ah[mi], bh[ni], acc[mi][ni], 0, 0, 0);
        acc[mi][ni] = __builtin_amdgcn_mfma_f32_16x16x32_bf16(ah[mi], bl[ni], acc[mi][ni], 0, 0, 0);
        acc[mi][ni] = __builtin_amdgcn_mfma_f32_16x16x32_bf16(al[mi], bh[ni], acc[mi][ni], 0, 0, 0);
      }
    __syncthreads();            // drains prefetch + guards reuse of cur
    cur ^= 1;
  }

  const int r4 = (lane >> 4) * 4;
#pragma unroll
  for (int mi = 0; mi < 2; mi++){
#pragma unroll
    for (int ni = 0; ni < 4; ni++){
      const int col = n0 + wn*64 + ni*16 + fr;
      const float bb = BIAS ? bias[zin*biasStride + col] : 0.f;
#pragma unroll
      for (int r = 0; r < 4; r++){
        const int row = m0 + wm*32 + mi*16 + r4 + r;
        float v = acc[mi][ni][r] + bb;
        if (EPI == 0){
          u16 hv = f2bf(v), lv = f2bf(v - bf2f(hv));
          long idx = coff + (long)row*ldc + col;
          ((u16*)Cv)[idx] = hv;
          ((u16*)Cv)[idx + loOffC] = lv;
        } else if (EPI == 1){
          ((float*)Cv)[coff + (long)row*ldc + col] = v;
        } else if (EPI == 2){
          long idx = coff + (long)row*ldc + col;
          ((float*)Cv)[idx] = v + Res[idx];
        } else if (EPI == 3){
          u16 hv = f2bf(v), lv = f2bf(v - bf2f(hv));
          int b = row >> 10, q = row & 1023;
          int h = col >> 8, d = col & 255;
          long o = ((long)(b*NHc + h)*HDc + d)*2048 + q;
          ((u16*)Cv)[o] = hv;
          ((u16*)Cv)[o + 1024] = lv;
        } else {                      // EPI==4: merged QKV
          u16 hv = f2bf(v), lv = f2bf(v - bf2f(hv));
          if (z < 2){
            long idx = (long)z*sCin + (long)row*ldc + col;
            ((u16*)Cv)[idx] = hv;
            ((u16*)Cv)[idx + loOffC] = lv;
          } else {
            int b = row >> 10, q = row & 1023;
            int h = col >> 8, d = col & 255;
            long o = sCout + ((long)(b*NHc + h)*HDc + d)*2048 + q;
            ((u16*)Cv)[o] = hv;
            ((u16*)Cv)[o + 1024] = lv;
          }
        }
      }
    }
  }
}

// ---------------------------------------------------------------------------
// Plain bf16 NT GEMM, dbuf, 512 threads / 8 waves (4x2), acc[2][4].
template<int EPI, int SKIP, int SWZ>
__global__ __launch_bounds__(512)
void gemm_bt(const u16* __restrict__ A, const u16* __restrict__ B,
             void* __restrict__ Cv,
             int M, int N, int K, int lda, int ldb, int ldc,
             long sAz, long sBz, long sCz, const int* __restrict__ tc)
{
  __shared__ u16 lsA[2][128*32];
  __shared__ u16 lsB[2][128*32];
  int m_i, n_i;
  if (SWZ == 2){ m_i = blockIdx.x; n_i = blockIdx.y; }
  else         { n_i = blockIdx.x; m_i = blockIdx.y; }
  const int z = blockIdx.z;
  int n0 = n_i*128, m0 = m_i*128;
  if (SKIP == 3){ if ((m0 & 1023) >= tc[m0 >> 10]) return; }
  if (SKIP == 4){ if (!compact_m0(tc, m_i, m0)) return; }
  const u16* Ab = A + (long)z*sAz;
  const u16* Bb = B + (long)z*sBz;
  const int t = threadIdx.x, lane = t & 63;
  const int w = t >> 6;
  const int wm = w >> 1, wn = w & 1;
  const int fr = lane & 15, kg = lane >> 4;
  const int srow = t >> 2, scol = (t & 3) * 8;
  f32x4 acc[2][4] = {};

  auto stage = [&](int buf, int kb){
    gload_lds16(Ab + (long)(m0 + srow)*lda + kb + scol, &lsA[buf][srow*32 + scol]);
    gload_lds16(Bb + (long)(n0 + srow)*ldb + kb + scol, &lsB[buf][srow*32 + scol]);
  };

  stage(0, 0);
  __syncthreads();
  int cur = 0;
  for (int kb = 0; kb < K; kb += 32){
    if (kb + 32 < K) stage(cur ^ 1, kb + 32);
    bf16x8 av[2], bv[4];
#pragma unroll
    for (int i = 0; i < 2; i++)
      av[i] = *(const bf16x8*)&lsA[cur][(wm*32 + i*16 + fr)*32 + kg*8];
#pragma unroll
    for (int j = 0; j < 4; j++)
      bv[j] = *(const bf16x8*)&lsB[cur][(wn*64 + j*16 + fr)*32 + kg*8];
#pragma unroll
    for (int mi = 0; mi < 2; mi++)
#pragma unroll
      for (int ni = 0; ni < 4; ni++)
        acc[mi][ni] = __builtin_amdgcn_mfma_f32_16x16x32_bf16(av[mi], bv[ni], acc[mi][ni], 0, 0, 0);
    __syncthreads();
    cur ^= 1;
  }

  const int r4 = (lane >> 4) * 4;
#pragma unroll
  for (int mi = 0; mi < 2; mi++){
#pragma unroll
    for (int ni = 0; ni < 4; ni++){
      const int col = n0 + wn*64 + ni*16 + fr;
#pragma unroll
      for (int r = 0; r < 4; r++){
        const int row = m0 + wm*32 + mi*16 + r4 + r;
        const long idx = (long)z*sCz + (long)row*ldc + col;
        float v = acc[mi][ni][r];
        if      (EPI == 0) ((u16*)Cv)[idx]   = f2bf(v);
        else if (EPI == 1) ((float*)Cv)[idx] = v;
        else               ((float*)Cv)[idx] += v;
      }
    }
  }
}

// ---------------------------------------------------------------------------
// Gathered GU GEMM (double-buffered, 256 thr): per expert e, rows from sidx
__global__ __launch_bounds__(256)
void gemm_gu_gather(const u16* __restrict__ A, const u16* __restrict__ Ball,
                    u16* __restrict__ Cg, const int* __restrict__ sidx,
                    const int* __restrict__ counts, const int* __restrict__ offs)
{
  __shared__ u16 lsA[2][128*32];
  __shared__ u16 lsB[2][128*32];
  const int e = blockIdx.z;
  const int cnt = counts[e];
  const int obase = offs[e];
  const int padc = offs[e+1] - obase;
  const int m0 = blockIdx.y*128;
  if (m0 >= padc) return;
  const int n0 = blockIdx.x*128;
  const u16* B = Ball + (long)e*512*1024;
  const int t = threadIdx.x, lane = t & 63;
  const int w = t >> 6, wm = w >> 1, wn = w & 1;
  const int fr = lane & 15, kg = lane >> 4;
  const int srow = t >> 2, scol = (t & 3) * 8;
  const int s0 = m0 + srow, s1 = m0 + 64 + srow;
  const int tok0 = (s0 < cnt) ? sidx[e*NTOK + s0] : 0;
  const int tok1 = (s1 < cnt) ? sidx[e*NTOK + s1] : 0;
  f32x4 acc[4][4] = {};

  auto stage = [&](int buf, int kb){
    gload_lds16(A + (long)tok0*1024 + kb + scol, &lsA[buf][srow*32 + scol]);
    gload_lds16(A + (long)tok1*1024 + kb + scol, &lsA[buf][(64+srow)*32 + scol]);
    gload_lds16(B + (long)(n0 +      srow)*1024 + kb + scol, &lsB[buf][srow*32 + scol]);
    gload_lds16(B + (long)(n0 + 64 + srow)*1024 + kb + scol, &lsB[buf][(64+srow)*32 + scol]);
  };

  stage(0, 0);
  __syncthreads();
  int cur = 0;
  for (int kb = 0; kb < 1024; kb += 32){
    if (kb + 32 < 1024) stage(cur ^ 1, kb + 32);
    bf16x8 av[4], bv[4];
#pragma unroll
    for (int i = 0; i < 4; i++){
      av[i] = *(const bf16x8*)&lsA[cur][(wm*64 + i*16 + fr)*32 + kg*8];
      bv[i] = *(const bf16x8*)&lsB[cur][(wn*64 + i*16 + fr)*32 + kg*8];
    }
#pragma unroll
    for (int mi = 0; mi < 4; mi++)
#pragma unroll
      for (int ni = 0; ni < 4; ni++)
        acc[mi][ni] = __builtin_amdgcn_mfma_f32_16x16x32_bf16(av[mi], bv[ni], acc[mi][ni], 0, 0, 0);
    __syncthreads();
    cur ^= 1;
  }

  const int r4 = (lane >> 4) * 4;
#pragma unroll
  for (int mi = 0; mi < 4; mi++){
#pragma unroll
    for (int ni = 0; ni < 4; ni++){
      const int col = wn*64 + ni*16 + fr + n0;
#pragma unroll
      for (int r = 0; r < 4; r++){
        const int row = m0 + wm*64 + mi*16 + r4 + r;
        Cg[(long)(obase + row)*512 + col] = f2bf(acc[mi][ni][r]);
      }
    }
  }
}

// Down GEMM dense over slot space (double-buffered, 256 thr)
__global__ __launch_bounds__(256)
void gemm_down_slots(const u16* __restrict__ Zg, const u16* __restrict__ Wd,
                     u16* __restrict__ D, const int* __restrict__ offs)
{
  __shared__ u16 lsA[2][128*32];
  __shared__ u16 lsB[2][128*32];
  const int m0 = blockIdx.y*128;
  if (m0 >= offs[8]) return;
  int e = 0;
#pragma unroll
  for (int i = 0; i < 7; i++) if (m0 >= offs[i+1]) e = i+1;
  const u16* B = Wd + (long)e*1024*256;
  const int n0 = blockIdx.x*128;
  const int t = threadIdx.x, lane = t & 63;
  const int w = t >> 6, wm = w >> 1, wn = w & 1;
  const int fr = lane & 15, kg = lane >> 4;
  const int srow = t >> 2, scol = (t & 3) * 8;
  f32x4 acc[4][4] = {};

  auto stage = [&](int buf, int kb){
    gload_lds16(Zg + (long)(m0 +      srow)*256 + kb + scol, &lsA[buf][srow*32 + scol]);
    gload_lds16(Zg + (long)(m0 + 64 + srow)*256 + kb + scol, &lsA[buf][(64+srow)*32 + scol]);
    gload_lds16(B  + (long)(n0 +      srow)*256 + kb + scol, &lsB[buf][srow*32 + scol]);
    gload_lds16(B  + (long)(n0 + 64 + srow)*256 + kb + scol, &lsB[buf][(64+srow)*32 + scol]);
  };

  stage(0, 0);
  __syncthreads();
  int cur = 0;
  for (int kb = 0; kb < 256; kb += 32){
    if (kb + 32 < 256) stage(cur ^ 1, kb + 32);
    bf16x8 av[4], bv[4];
#pragma unroll
    for (int i = 0; i < 4; i++){
      av[i] = *(const bf16x8*)&lsA[cur][(wm*64 + i*16 + fr)*32 + kg*8];
      bv[i] = *(const bf16x8*)&lsB[cur][(wn*64 + i*16 + fr)*32 + kg*8];
    }
#pragma unroll
    for (int mi = 0; mi < 4; mi++)
#pragma unroll
      for (int ni = 0; ni < 4; ni++)
        acc[mi][ni] = __builtin_amdgcn_mfma_f32_16x16x32_bf16(av[mi], bv[ni], acc[mi][ni], 0, 0, 0);
    __syncthreads();
    cur ^= 1;
  }

  const int r4 = (lane >> 4) * 4;
#pragma unroll
  for (int mi = 0; mi < 4; mi++){
#pragma unroll
    for (int ni = 0; ni < 4; ni++){
      const int col = n0 + wn*64 + ni*16 + fr;
#pragma unroll
      for (int r = 0; r < 4; r++){
        const int row = m0 + wm*64 + mi*16 + r4 + r;
        D[(long)row*1024 + col] = f2bf(acc[mi][ni][r]);
      }
    }
  }
}

// ---------------------------------------------------------------------------
// FUSED input prep: per-block token-row rmsnorm (hi|lo pack) + grid-stride
// weight prep (Wqkv/Woutp splits, Wed/Wsg/Wsu/Wsd casts, expert-norm fold).
// Replaces 2 launches; all segments independent, identical math.
__global__ __launch_bounds__(256)
void prep_norm_k(const float* __restrict__ x, const float* __restrict__ w1,
                 u16* __restrict__ o,
                 const float* __restrict__ Wqkv, const float* __restrict__ Woutp,
                 const float* __restrict__ Wed, const float* __restrict__ Wsg,
                 const float* __restrict__ Wsu, const float* __restrict__ Wsd,
                 const float* __restrict__ Weg, const float* __restrict__ Weu,
                 const float* __restrict__ nw,
                 u16* __restrict__ qH, u16* __restrict__ qL,
                 u16* __restrict__ oH, u16* __restrict__ oL,
                 u16* __restrict__ wd, u16* __restrict__ sgu,
                 u16* __restrict__ sd, u16* __restrict__ gu){
  const int row = blockIdx.x, t = threadIdx.x, lane = t & 63, w = t >> 6;
  // --- token-row rmsnorm -> packed hi|lo ---
  float4 v = ((const float4*)(x + (long)row*Hc))[t];
  float ss = v.x*v.x + v.y*v.y + v.z*v.z + v.w*v.w;
  for (int off = 32; off; off >>= 1) ss += __shfl_xor(ss, off);
  __shared__ float red[4];
  if (lane == 0) red[w] = ss;
  __syncthreads();
  float rs = rsqrtf((red[0]+red[1]+red[2]+red[3])*(1.f/Hc) + EPSc);
  float4 wv = ((const float4*)w1)[t];
  float f0 = v.x*rs*wv.x, f1 = v.y*rs*wv.y, f2 = v.z*rs*wv.z, f3 = v.w*rs*wv.w;
  ushort4 hv, lv;
  hv.x = f2bf(f0); lv.x = f2bf(f0 - bf2f(hv.x));
  hv.y = f2bf(f1); lv.y = f2bf(f1 - bf2f(hv.y));
  hv.z = f2bf(f2); lv.z = f2bf(f2 - bf2f(hv.z));
  hv.w = f2bf(f3); lv.w = f2bf(f3 - bf2f(hv.w));
  u16* r16 = o + (long)row*2048;
  ((ushort4*)r16)[t] = hv;
  ((ushort4*)(r16 + 1024))[t] = lv;

  // --- grid-stride weight prep ---
  const long st = (long)gridDim.x*blockDim.x;            // 8192*256
  const long i0 = (long)row*blockDim.x + t;
  const long nQ = 3145728, nO = 1048576, nD = 2097152, nS = 524288, nG = 2097152;
  for (long j = i0; j < nQ; j += st){
    float q = Wqkv[j]; u16 h = f2bf(q); qH[j] = h; qL[j] = f2bf(q - bf2f(h));
  }
  for (long j = i0; j < nO; j += st){
    float q = Woutp[j]; u16 h = f2bf(q); oH[j] = h; oL[j] = f2bf(q - bf2f(h));
  }
  for (long j = i0; j < nD; j += st) wd[j] = f2bf(Wed[j]);
  for (long j = i0; j < nS; j += st){
    sgu[j]      = f2bf(Wsg[j]);
    sgu[j + nS] = f2bf(Wsu[j]);
    sd[j]       = f2bf(Wsd[j]);
  }
  for (long j = i0; j < nG; j += st){
    int h  = (int)(j & (Hc - 1));
    int ii = (int)((j >> 10) & (Ic - 1));
    int e  = (int)(j >> 18);
    float wvv = nw[e*Hc + h];
    long oo = (long)e*(2*Ic*Hc) + (long)ii*Hc + h;
    gu[oo]         = f2bf(Weg[j]*wvv);
    gu[oo + Ic*Hc] = f2bf(Weu[j]*wvv);
  }
}

// fused rmsnorm (xhat w=1, sx with shared_norm_w) + gating top-2 per token row
__global__ __launch_bounds__(256)
void norm_gate_k(const float* __restrict__ x, const float* __restrict__ shw,
                 const float* __restrict__ gnw, const float* __restrict__ gw,
                 const int* __restrict__ tcnt,
                 u16* __restrict__ xhat, u16* __restrict__ sx,
                 int* __restrict__ topi, float* __restrict__ topw){
  const int row = blockIdx.x, t = threadIdx.x, lane = t & 63, w = t >> 6;
  float4 v = ((const float4*)(x + (long)row*Hc))[t];
  float ss = v.x*v.x + v.y*v.y + v.z*v.z + v.w*v.w;
  for (int off = 32; off; off >>= 1) ss += __shfl_xor(ss, off);
  __shared__ float red[4];
  __shared__ float gred[4][8];
  if (lane == 0) red[w] = ss;
  __syncthreads();
  float rs = rsqrtf((red[0]+red[1]+red[2]+red[3])*(1.f/Hc) + EPSc);
  ushort4 ov;
  ov.x = f2bf(v.x*rs); ov.y = f2bf(v.y*rs); ov.z = f2bf(v.z*rs); ov.w = f2bf(v.w*rs);
  ((ushort4*)xhat)[(long)row*256 + t] = ov;
  float4 sv = ((const float4*)shw)[t];
  ov.x = f2bf(v.x*rs*sv.x); ov.y = f2bf(v.y*rs*sv.y);
  ov.z = f2bf(v.z*rs*sv.z); ov.w = f2bf(v.w*rs*sv.w);
  ((ushort4*)sx)[(long)row*256 + t] = ov;

  const int b = row >> 10, l = row & 1023;
  if (l >= tcnt[b]) return;
  float4 g = ((const float4*)gnw)[t];
  float xg0 = v.x*g.x, xg1 = v.y*g.y, xg2 = v.z*g.z, xg3 = v.w*g.w;
  float pe[8];
#pragma unroll
  for (int e = 0; e < 8; e++){
    float4 ww = ((const float4*)(gw + (long)e*Hc))[t];
    pe[e] = xg0*ww.x + xg1*ww.y + xg2*ww.z + xg3*ww.w;
  }
  for (int off = 32; off; off >>= 1){
#pragma unroll
    for (int e = 0; e < 8; e++) pe[e] += __shfl_xor(pe[e], off);
  }
  if (lane == 0){
#pragma unroll
    for (int e = 0; e < 8; e++) gred[w][e] = pe[e];
  }
  __syncthreads();
  if (t == 0){
    float sc[8], m = -3.4e38f;
#pragma unroll
    for (int e = 0; e < 8; e++){
      sc[e] = (gred[0][e]+gred[1][e]+gred[2][e]+gred[3][e])*rs;
      m = fmaxf(m, sc[e]);
    }
    float p[8], sum = 0.f;
#pragma unroll
    for (int e = 0; e < 8; e++){ p[e] = __expf(sc[e] - m); sum += p[e]; }
    float inv = 1.f/sum;
#pragma unroll
    for (int e = 0; e < 8; e++) p[e] *= inv;
    int i1 = 0; float v1 = p[0];
#pragma unroll
    for (int e = 1; e < 8; e++) if (p[e] > v1){ v1 = p[e]; i1 = e; }
    int i2 = -1; float v2 = -1.f;
#pragma unroll
    for (int e = 0; e < 8; e++) if (e != i1 && p[e] > v2){ v2 = p[e]; i2 = e; }
    float dn = v1 + v2 + 1e-20f;
    topi[2*row] = i1; topi[2*row + 1] = i2;
    topw[2*row] = v1/dn; topw[2*row + 1] = v2/dn;
  }
}

// masked softmax; skips padded q rows. b = bbase + ((rid>>10) & bmask)
__global__ __launch_bounds__(256)
void softmax2_k(float* __restrict__ S, const int* __restrict__ cnt, int bbase, int bmask){
  const int rid = blockIdx.x;
  const int b = bbase + ((rid >> 10) & bmask);
  const int n = cnt[b];
  if ((rid & 1023) >= n) return;
  float* row = S + (long)rid*Lc;
  const int t = threadIdx.x, lane = t & 63, w = t >> 6;
  float4 v = ((const float4*)row)[t];
  const float sc = 0.0625f;
  float vals[4] = {v.x*sc, v.y*sc, v.z*sc, v.w*sc};
  const int c = t*4;
  float m = -3.4e38f;
#pragma unroll
  for (int j = 0; j < 4; j++) if (c + j < n) m = fmaxf(m, vals[j]);
  for (int o = 32; o; o >>= 1) m = fmaxf(m, __shfl_xor(m, o));
  __shared__ float red[8];
  if (lane == 0) red[w] = m;
  __syncthreads();
  m = fmaxf(fmaxf(red[0], red[1]), fmaxf(red[2], red[3]));
  float p[4], s = 0.f;
#pragma unroll
  for (int j = 0; j < 4; j++){ p[j] = (c + j < n) ? __expf(vals[j] - m) : 0.f; s += p[j]; }
  for (int o = 32; o; o >>= 1) s += __shfl_xor(s, o);
  if (lane == 0) red[4 + w] = s;
  __syncthreads();
  const float inv = 1.f / (red[4]+red[5]+red[6]+red[7]);
  ushort4 hv, lv;
  float q0 = p[0]*inv, q1 = p[1]*inv, q2 = p[2]*inv, q3 = p[3]*inv;
  hv.x = f2bf(q0); lv.x = f2bf(q0 - bf2f(hv.x));
  hv.y = f2bf(q1); lv.y = f2bf(q1 - bf2f(hv.y));
  hv.z = f2bf(q2); lv.z = f2bf(q2 - bf2f(hv.z));
  hv.w = f2bf(q3); lv.w = f2bf(q3 - bf2f(hv.w));
  u16* r16 = (u16*)S + (long)rid*2048;
  ((ushort4*)r16)[t] = hv;
  ((ushort4*)(r16 + 1024))[t] = lv;
}

// deterministic routing build: single block, 1024 threads, token-ordered.
__global__ __launch_bounds__(1024)
void route_scan_k(const int* __restrict__ tcnt, const int* __restrict__ topi,
                  const float* __restrict__ topw, int* __restrict__ counts,
                  int* __restrict__ offs, int* __restrict__ sidx,
                  int* __restrict__ gpos, float* __restrict__ wG){
  __shared__ int hist[1024][8];
  __shared__ int soffs[9];
  const int t = threadIdx.x;
  for (int i = t; i < MAXSLOTS; i += 1024) wG[i] = 0.f;
  int h[8] = {0,0,0,0,0,0,0,0};
  const int n0 = t*8;
  int e0[8], e1[8];
#pragma unroll
  for (int k = 0; k < 8; k++){
    const int n = n0 + k;
    const int b = n >> 10, l = n & 1023;
    const bool val = l < tcnt[b];
    e0[k] = val ? topi[2*n]   : -1;
    e1[k] = val ? topi[2*n+1] : -1;
    if (val){ h[e0[k]]++; h[e1[k]]++; }
  }
#pragma unroll
  for (int e = 0; e < 8; e++) hist[t][e] = h[e];
  __syncthreads();
  for (int off = 1; off < 1024; off <<= 1){
    int v[8];
#pragma unroll
    for (int e = 0; e < 8; e++)
      v[e] = hist[t][e] + ((t >= off) ? hist[t - off][e] : 0);
    __syncthreads();
#pragma unroll
    for (int e = 0; e < 8; e++) hist[t][e] = v[e];
    __syncthreads();
  }
  if (t == 0){
    int o = 0; soffs[0] = 0; offs[0] = 0;
    for (int e = 0; e < 8; e++){
      int c = hist[1023][e];
      counts[e] = c;
      o += (c + 127) & ~127;
      soffs[e+1] = o;
      offs[e+1] = o;
    }
  }
  __syncthreads();
  int run[8];
#pragma unroll
  for (int e = 0; e < 8; e++) run[e] = hist[t][e] - h[e];
#pragma unroll
  for (int k = 0; k < 8; k++){
    const int n = n0 + k;
    if (e0[k] >= 0){
      const int p0 = run[e0[k]]++;
      const int p1 = run[e1[k]]++;
      sidx[e0[k]*NTOK + p0] = n;
      sidx[e1[k]*NTOK + p1] = n;
      const int g0 = soffs[e0[k]] + p0, g1 = soffs[e1[k]] + p1;
      gpos[2*n] = g0; gpos[2*n+1] = g1;
      wG[g0] = topw[2*n]; wG[g1] = topw[2*n+1];
    } else {
      gpos[2*n] = 0; gpos[2*n+1] = 0;
    }
  }
}

__global__ void act_shared_k(const u16* __restrict__ gu, u16* __restrict__ z, long n){
  long i = (long)blockIdx.x*blockDim.x + threadIdx.x;
  long st = (long)gridDim.x*blockDim.x;
  for (; i < n; i += st){
    long nn = i >> 9;
    int  ii = (int)(i & (ISc - 1));
    float gv = bf2f(gu[nn*1024 + ii]);
    float uv = bf2f(gu[nn*1024 + ISc + ii]);
    z[i] = f2bf(gv/(1.f + __expf(-gv)) * uv);
  }
}

__global__ void act_slots_k(const u16* __restrict__ gu, const float* __restrict__ wG,
                            const int* __restrict__ offs, u16* __restrict__ z){
  long nmax = (long)offs[8]*256;
  long st = (long)gridDim.x*blockDim.x;
  for (long i = (long)blockIdx.x*blockDim.x + threadIdx.x; i < nmax; i += st){
    long s = i >> 8;
    int ii = (int)(i & 255);
    float gv = bf2f(gu[s*512 + ii]);
    float uv = bf2f(gu[s*512 + 256 + ii]);
    z[i] = f2bf(gv/(1.f + __expf(-gv)) * uv * wG[s]);
  }
}

__global__ void act_expert_k(const u16* __restrict__ gu, const int* __restrict__ topi,
                             const float* __restrict__ topw, int e,
                             u16* __restrict__ z, long n){
  long i = (long)blockIdx.x*blockDim.x + threadIdx.x;
  long st = (long)gridDim.x*blockDim.x;
  for (; i < n; i += st){
    long nn = i >> 8;
    int  ii = (int)(i & (Ic - 1));
    float wv = 0.f;
    if      (topi[2*nn]     == e) wv = topw[2*nn];
    else if (topi[2*nn + 1] == e) wv = topw[2*nn + 1];
    float gv = bf2f(gu[nn*512 + ii]);
    float uv = bf2f(gu[nn*512 + Ic + ii]);
    z[i] = f2bf(gv/(1.f + __expf(-gv)) * uv * wv);
  }
}

__global__ __launch_bounds__(256)
void final2_k(const float* __restrict__ ysh, const u16* __restrict__ D,
              const int* __restrict__ gpos, const float* __restrict__ ogw,
              const float* __restrict__ ogb, const int* __restrict__ cnt,
              float* __restrict__ out){
  const int t = threadIdx.x, lane = t & 63, w = t >> 6;
  const int n = blockIdx.x*4 + w;
  const int b = n >> 10, l = n & 1023;
  float* outr = out + (long)n*Hc;
  if (l >= cnt[b]){
#pragma unroll
    for (int j = 0; j < 16; j++) outr[j*64 + lane] = 0.f;
    return;
  }
  const float* yr = ysh + (long)n*Hc;
  const u16* d0 = D + (long)gpos[2*n]*1024;
  const u16* d1 = D + (long)gpos[2*n+1]*1024;
  float dot = 0.f, yv[16];
#pragma unroll
  for (int j = 0; j < 16; j++){
    int d = j*64 + lane;
    yv[j] = yr[d] + bf2f(d0[d]) + bf2f(d1[d]);
    dot += yv[j]*ogw[d];
  }
  for (int o = 32; o; o >>= 1) dot += __shfl_xor(dot, o);
  float s = 1.f/(1.f + __expf(-(dot + ogb[0])));
#pragma unroll
  for (int j = 0; j < 16; j++) outr[j*64 + lane] = yv[j]*s;
}

__global__ __launch_bounds__(256)
void final_k(const float* __restrict__ y, const float* __restrict__ ogw,
             const float* __restrict__ ogb, const int* __restrict__ cnt,
             float* __restrict__ out){
  const int t = threadIdx.x, lane = t & 63, w = t >> 6;
  const int n = blockIdx.x*4 + w;
  const int b = n >> 10, l = n & 1023;
  const bool pad = l >= cnt[b];
  const float* yr = y + (long)n*Hc;
  float dot = 0.f, yv[16];
#pragma unroll
  for (int j = 0; j < 16; j++){
    int d = j*64 + lane;
    yv[j] = yr[d];
    dot += yv[j]*ogw[d];
  }
  for (int o = 32; o; o >>= 1) dot += __shfl_xor(dot, o);
  float s = 1.f/(1.f + __expf(-(dot + ogb[0])));
  float* outr = out + (long)n*Hc;
#pragma unroll
  for (int j = 0; j < 16; j++){
    int d = j*64 + lane;
    outr[d] = pad ? 0.f : yv[j]*s;
  }
}

__global__ void sentinel_k(float* out){ out[0] = 1.0e9f; }

// ---------------------------------------------------------------------------
extern "C" void kernel_launch(void* const* d_in, const int* in_sizes, int n_in,
                              void* d_out, int out_size, void* d_ws, size_t ws_size,
                              hipStream_t stream){
  const float* hidden  = (const float*)d_in[0];
  const int*   cnt     = (const int*)  d_in[1];
  const float* ctx_nw  = (const float*)d_in[2];
  const float* Wqkv    = (const float*)d_in[3];
  const float* in_b    = (const float*)d_in[4];
  const float* Woutp   = (const float*)d_in[5];
  const float* out_b   = (const float*)d_in[6];
  const float* gate_nw = (const float*)d_in[7];
  const float* gate_w  = (const float*)d_in[8];
  const float* exp_nw  = (const float*)d_in[9];
  const float* Weg     = (const float*)d_in[10];
  const float* Weu     = (const float*)d_in[11];
  const float* Wed     = (const float*)d_in[12];
  const float* sh_nw   = (const float*)d_in[13];
  const float* Wsg     = (const float*)d_in[14];
  const float* Wsu     = (const float*)d_in[15];
  const float* Wsd     = (const float*)d_in[16];
  const float* ogw     = (const float*)d_in[17];
  const float* ogb     = (const float*)d_in[18];
  float* out = (float*)d_out;

  const size_t MB = 1024*1024;
  char* ws = (char*)d_ws;
  size_t off = 0;
  auto alloc = [&](size_t bytes)->char*{
    char* p = ws + off; off += (bytes + 255) & ~(size_t)255; return p;
  };
  u16* wWqH  = (u16*)alloc((size_t)3072*1024*2);
  u16* wWqL  = (u16*)alloc((size_t)3072*1024*2);
  u16* wWoH  = (u16*)alloc((size_t)1024*1024*2);
  u16* wWoL  = (u16*)alloc((size_t)1024*1024*2);
  u16* wWgu  = (u16*)alloc((size_t)Ec*2*Ic*Hc*2);
  u16* wWd   = (u16*)alloc((size_t)Ec*Hc*Ic*2);
  u16* wWsgu = (u16*)alloc((size_t)2*ISc*Hc*2);
  u16* wWsd  = (u16*)alloc((size_t)Hc*ISc*2);
  int*   wTopI = (int*)  alloc((size_t)NTOK*2*4);
  float* wTopW = (float*)alloc((size_t)NTOK*2*4);
  int*   wGpos = (int*)  alloc((size_t)NTOK*2*4);
  int*   wSidx = (int*)  alloc((size_t)Ec*NTOK*4);
  float* wG    = (float*)alloc((size_t)MAXSLOTS*4);
  int*   wCnts = (int*)  alloc(64);
  int*   wOffs = (int*)  alloc(64);
  char* P1 = alloc(32*MB);
  char* P2 = alloc(32*MB);   // Qp
  char* P3 = alloc(32*MB);   // Kp  (= P2 + 32MB)
  char* P4 = alloc(32*MB);   // Vtp (= P2 + 64MB)
  size_t fixed = off;
  const int mode = (fixed + 128*MB <= ws_size) ? 2 :
                   (fixed + 64*MB  <= ws_size) ? 1 : 0;
  char* P5 = alloc(mode == 2 ? 128*MB : mode == 1 ? 64*MB : 16*MB);
  if (off > ws_size){ sentinel_k<<<1,1,0,stream>>>(out); return; }

  u16*   wNx   = (u16*)P1;
  u16*   wCtx  = (u16*)P1;
  float* wY    = (float*)P1;
  u16*   wQp   = (u16*)P2;
  u16*   wXhat = (u16*)P2;
  u16*   wSx   = (u16*)(P2 + 16*MB);
  u16*   wKp   = (u16*)P3;
  float* wX    = (float*)P3;
  u16*   wGUg  = (u16*)P3;
  u16*   wZg   = (u16*)(P3 + 18*MB);
  u16*   wGUe  = (u16*)P3;
  u16*   wZe   = (u16*)(P3 + 8*MB);
  u16*   wVtp  = (u16*)P4;
  u16*   wGUs  = (u16*)P4;
  u16*   wZs   = (u16*)(P4 + 16*MB);
  float* wS    = (float*)P5;
  u16*   wD    = (u16*)P5;

  // 1+2a) fused: pre-attn rmsnorm (hi|lo pack) + ALL weight prep (1 launch)
  prep_norm_k<<<NTOK, 256, 0, stream>>>(hidden, ctx_nw, wNx,
                                        Wqkv, Woutp, Wed, Wsg, Wsu, Wsd,
                                        Weg, Weu, exp_nw,
                                        wWqH, wWqL, wWoH, wWoL, wWd,
                                        wWsgu, wWsd, wWgu);

  // 2b) MERGED Q/K/V projection (compact-live grid, 512 thr)
  gemm3<4, 1, 4, 2, 0><<<dim3(64, 8, 3), 512, 0, stream>>>(
      wNx, wNx + 1024, wWqH, wWqL, wQp, in_b, nullptr,
      NTOK, 1024, 1024, 2048, 1024, 2048,
      0, 0, (long)1024*1024, 0,
      (long)16*1024*1024,        // z stride Qp->Kp (u16)
      (long)32*1024*1024,        // V base offset from Qp (u16)
      1024, 1024, cnt, 0);

  // 3) attention
  if (mode == 2){
    gemm3<1, 0, 1, 1, 1><<<dim3(8, 8, 32), 512, 0, stream>>>(
        wQp, wQp + 1024, wKp, wKp + 1024, wS, nullptr, nullptr,
        Lc, Lc, HDc, 2048, 2048, Lc,
        (long)Lc*2048, (long)HDc,
        (long)Lc*2048, (long)HDc,
        (long)Lc*Lc,   (long)8*Lc*Lc,
        0, 0, cnt, 0);
    softmax2_k<<<32*1024, 256, 0, stream>>>(wS, cnt, 0, 7);
    gemm3<0, 0, 2, 1, 1><<<dim3(2, 8, 32), 512, 0, stream>>>(
        (const u16*)wS, (const u16*)wS + 1024, wVtp, wVtp + 1024, wCtx,
        nullptr, nullptr,
        Lc, HDc, Lc, 2048, 2048, 2048,
        (long)Lc*2048,      (long)8*Lc*2048,
        (long)NHc*HDc*2048, (long)HDc*2048,
        (long)Lc*2048,      (long)HDc,
        1024, 0, cnt, 0);
  } else if (mode == 1){
    for (int g = 0; g < 2; g++){
      const int bbase = g*4;
      const long tokoff = (long)g*4*Lc*2048;
      const u16* Qb = wQp + tokoff;
      const u16* Kb = wKp + tokoff;
      gemm3<1, 0, 1, 1, 0><<<dim3(8, 8, 16), 512, 0, stream>>>(
          Qb, Qb + 1024, Kb, Kb + 1024, wS, nullptr, nullptr,
          Lc, Lc, HDc, 2048, 2048, Lc,
          (long)Lc*2048, (long)HDc,
          (long)Lc*2048, (long)HDc,
          (long)Lc*Lc,   (long)4*Lc*Lc,
          0, 0, cnt, bbase);
      softmax2_k<<<16*1024, 256, 0, stream>>>(wS, cnt, bbase, 3);
      const u16* Vb = wVtp + (long)g*4*NHc*HDc*2048;
      u16* Cb = wCtx + tokoff;
      gemm3<0, 0, 2, 1, 0><<<dim3(2, 8, 16), 512, 0, stream>>>(
          (const u16*)wS, (const u16*)wS + 1024, Vb, Vb + 1024, Cb, nullptr, nullptr,
          Lc, HDc, Lc, 2048, 2048, 2048,
          (long)Lc*2048,     (long)4*Lc*2048,
          (long)NHc*HDc*2048,(long)HDc*2048,
          (long)Lc*2048,     (long)HDc,
          1024, 0, cnt, bbase);
    }
  } else {
    for (int g = 0; g < 8; g++){
      const int hf = g >> 2, hbase = g & 3, bbase = hf*4;
      const long tokoff = (long)hf*4*Lc*2048;
      const u16* Qb = wQp + tokoff + hbase*HDc;
      const u16* Kb = wKp + tokoff + hbase*HDc;
      gemm3<1, 0, 1, 0, 0><<<dim3(8, 8, 4), 512, 0, stream>>>(
          Qb, Qb + 1024, Kb, Kb + 1024, wS, nullptr, nullptr,
          Lc, Lc, HDc, 2048, 2048, Lc,
          (long)Lc*2048, (long)HDc,
          (long)Lc*2048, (long)HDc,
          (long)Lc*Lc,   (long)4*Lc*Lc,
          0, 0, cnt, bbase);
      softmax2_k<<<4*1024, 256, 0, stream>>>(wS, cnt, bbase, 3);
      const u16* Vb = wVtp + (long)hf*4*NHc*HDc*2048 + (long)hbase*HDc*2048;
      u16* Cb = wCtx + tokoff + hbase*HDc;
      gemm3<0, 0, 2, 0, 0><<<dim3(2, 8, 4), 512, 0, stream>>>(
          (const u16*)wS, (const u16*)wS + 1024, Vb, Vb + 1024, Cb, nullptr, nullptr,
          Lc, HDc, Lc, 2048, 2048, 2048,
          (long)Lc*2048,     (long)4*Lc*2048,
          (long)NHc*HDc*2048,(long)HDc*2048,
          (long)Lc*2048,     (long)HDc,
          1024, 0, cnt, bbase);
    }
  }

  // 4) out-proj + bias + residual -> X f32 (compact-live grid)
  gemm3<2, 1, 4, 2, 0><<<dim3(64, 8, 1), 512, 0, stream>>>(
      wCtx, wCtx + 1024, wWoH, wWoL, wX, out_b, hidden,
      NTOK, 1024, 1024, 2048, 1024, 1024,
      0, 0, 0, 0, 0, 0, 0, 0, cnt, 0);

  // 5) fused rmsnorm + gating, then deterministic route build
  norm_gate_k<<<NTOK, 256, 0, stream>>>(wX, sh_nw, gate_nw, gate_w, cnt,
                                        wXhat, wSx, wTopI, wTopW);
  route_scan_k<<<1, 1024, 0, stream>>>(cnt, wTopI, wTopW, wCnts, wOffs,
                                       wSidx, wGpos, wG);

  // 6) shared experts -> Y (compact-live grid, 512 thr)
  gemm_bt<0, 4, 2><<<dim3(64, 8, 1), 512, 0, stream>>>(
      wSx, wWsgu, wGUs, NTOK, 2*ISc, 1024, 1024, 1024, 2*ISc, 0, 0, 0, cnt);
  act_shared_k<<<4096, 256, 0, stream>>>(wGUs, wZs, (long)NTOK*ISc);
  gemm_bt<1, 4, 2><<<dim3(64, 8, 1), 512, 0, stream>>>(
      wZs, wWsd, wY, NTOK, 1024, ISc, ISc, ISc, 1024, 0, 0, 0, cnt);

  // 7) routed experts
  if (mode >= 1){
    gemm_gu_gather<<<dim3(4, 64, Ec), 256, 0, stream>>>(
        wXhat, wWgu, wGUg, wSidx, wCnts, wOffs);
    act_slots_k<<<2048, 256, 0, stream>>>(wGUg, wG, wOffs, wZg);
    gemm_down_slots<<<dim3(8, MAXSLOTS/128, 1), 256, 0, stream>>>(
        wZg, wWd, wD, wOffs);
    final2_k<<<NTOK/4, 256, 0, stream>>>(wY, wD, wGpos, ogw, ogb, cnt, out);
  } else {
    for (int e = 0; e < Ec; e++){
      gemm_bt<0, 0, 0><<<dim3(4, 64, 1), 512, 0, stream>>>(
          wXhat, wWgu + (long)e*2*Ic*Hc, wGUe, NTOK, 2*Ic, 1024, 1024, 1024, 2*Ic,
          0, 0, 0, nullptr);
      act_expert_k<<<2048, 256, 0, stream>>>(wGUe, wTopI, wTopW, e, wZe, (long)NTOK*Ic);
      gemm_bt<2, 0, 0><<<dim3(8, 64, 1), 512, 0, stream>>>(
          wZe, wWd + (long)e*Hc*Ic, wY, NTOK, 1024, Ic, Ic, Ic, 1024, 0, 0, 0, nullptr);
    }
    final_k<<<NTOK/4, 256, 0, stream>>>(wY, ogw, ogb, cnt, out);
  }
}

// Round 22
// 574.476 us; speedup vs baseline: 1.0045x; 1.0045x over previous
//
#include <hip/hip_runtime.h>
#include <hip/hip_bf16.h>

typedef unsigned short u16;
typedef unsigned int   u32;
typedef short bf16x8 __attribute__((ext_vector_type(8)));
typedef float f32x4  __attribute__((ext_vector_type(4)));

#define DEV static __device__ __forceinline__

#define Bc 8
#define Lc 1024
#define Hc 1024
#define Ec 8
#define Ic 256
#define ISc 512
#define NHc 4
#define HDc 256
#define NTOK 8192
#define EPSc 1e-6f
#define MAXSLOTS 17408

DEV u16 f2bf(float f){
  u32 u = __float_as_uint(f);
  return (u16)((u + 0x7fffu + ((u >> 16) & 1u)) >> 16);
}
DEV float bf2f(u16 h){ return __uint_as_float(((u32)h) << 16); }

DEV void gload_lds16(const void* g, void* l){
  __builtin_amdgcn_global_load_lds((const __attribute__((address_space(1))) u32*)g,
                                   (__attribute__((address_space(3))) u32*)l, 16, 0, 0);
}

// compact live m-block remap: slot in [0,64) -> live block i = (slot&7)+8*(slot>>3)
DEV bool compact_m0(const int* __restrict__ tc, int slot, int& m0){
  int cb[8], Lt = 0;
#pragma unroll
  for (int b = 0; b < 8; b++){ cb[b] = (tc[b] + 127) >> 7; Lt += cb[b]; }
  const int i = (slot & 7) + 8*(slot >> 3);
  if (i >= Lt) return false;
  int acc = 0, bsel = 0, pos = 0;
#pragma unroll
  for (int b = 0; b < 8; b++){
    if (i < acc + cb[b]){ bsel = b; pos = i - acc; break; }
    acc += cb[b];
  }
  m0 = (bsel*8 + pos)*128;
  return true;
}

// ---------------------------------------------------------------------------
// Split-precision NT GEMM: 4-plane LDS double-buffer (round-14 optimum),
// 512 thr / 8 waves (4x2), wave tile 32x64 (acc[2][4]).
// EPI: 0 packed hi|lo (lo at +loOffC), 1 f32, 2 f32 acc+bias+Res,
//      3 V-transpose packed, 4 merged QKV
// SKIP: 0 none; 1 attn QK; 2 attn PV (K clamp); 3 pad-row; 4 compact-live
// SWZ: 0 (x=n,y=m); 1 slice->XCD; 2 transposed (x=m/slot)
// ZDEC: 0 zin=z&3; 1 zin=z&7
// ---------------------------------------------------------------------------
template<int EPI, int BIAS, int SKIP, int SWZ, int ZDEC>
__global__ __launch_bounds__(512)
void gemm3(const u16* __restrict__ Ahi, const u16* __restrict__ Alo,
           const u16* __restrict__ Bhi, const u16* __restrict__ Blo,
           void* __restrict__ Cv, const float* __restrict__ bias,
           const float* __restrict__ Res,
           int M, int N, int K, int lda, int ldb, int ldc,
           long sAin, long sAout, long sBin, long sBout, long sCin, long sCout,
           int loOffC, int biasStride, const int* __restrict__ tc, int bbase)
{
  __shared__ u16 lsAh[2][128*32];
  __shared__ u16 lsAl[2][128*32];
  __shared__ u16 lsBh[2][128*32];
  __shared__ u16 lsBl[2][128*32];
  int m_i, n_i, z;
  if (SWZ == 1){
    const int NB = gridDim.x*gridDim.y;
    const int L = blockIdx.x + gridDim.x*(blockIdx.y + gridDim.y*blockIdx.z);
    const int r = L & 7, k = L >> 3;
    z = r + 8*(k / NB);
    const int idx = k % NB;
    n_i = idx % gridDim.x; m_i = idx / gridDim.x;
  } else if (SWZ == 2){
    m_i = blockIdx.x; n_i = blockIdx.y; z = blockIdx.z;
  } else {
    n_i = blockIdx.x; m_i = blockIdx.y; z = blockIdx.z;
  }
  int n0 = n_i*128, m0 = m_i*128;
  const int zin  = ZDEC ? (z & 7)  : (z & 3);
  const int zout = ZDEC ? (z >> 3) : (z >> 2);
  if (SKIP == 1){ const int c = tc[bbase + zin]; if (m0 >= c || n0 >= c) return; }
  if (SKIP == 2){ const int c = tc[bbase + zin]; if (m0 >= c) return;
                  const int kl = (c + 31) & ~31; K = K < kl ? K : kl; }
  if (SKIP == 3){ if ((m0 & 1023) >= tc[m0 >> 10]) return; }
  if (SKIP == 4){ if (!compact_m0(tc, m_i, m0)) return; }
  const long aoff = (long)zin*sAin + (long)zout*sAout;
  const long boff = (long)zin*sBin + (long)zout*sBout;
  const long coff = (long)zin*sCin + (long)zout*sCout;
  const u16* Ahb = Ahi + aoff;
  const u16* Alb = Alo + aoff;
  const u16* Bhb = Bhi + boff;
  const u16* Blb = Blo + boff;
  const int t = threadIdx.x, lane = t & 63;
  const int w = t >> 6;                 // 8 waves
  const int wm = w >> 1, wn = w & 1;    // 4x2 wave grid: 32-row x 64-col tiles
  const int fr = lane & 15, kg = lane >> 4;
  const int srow = t >> 2, scol = (t & 3) * 8;   // 512 thr: 128 rows x 64B
  f32x4 acc[2][4] = {};

  auto stage = [&](int buf, int kb){
    gload_lds16(Ahb + (long)(m0 + srow)*lda + kb + scol, &lsAh[buf][srow*32 + scol]);
    gload_lds16(Alb + (long)(m0 + srow)*lda + kb + scol, &lsAl[buf][srow*32 + scol]);
    gload_lds16(Bhb + (long)(n0 + srow)*ldb + kb + scol, &lsBh[buf][srow*32 + scol]);
    gload_lds16(Blb + (long)(n0 + srow)*ldb + kb + scol, &lsBl[buf][srow*32 + scol]);
  };

  stage(0, 0);
  __syncthreads();              // implicit vmcnt(0): buf0 ready
  int cur = 0;
  for (int kb = 0; kb < K; kb += 32){
    if (kb + 32 < K) stage(cur ^ 1, kb + 32);   // prefetch next tile first
    bf16x8 ah[2], al[2], bh[4], bl[4];
#pragma unroll
    for (int i = 0; i < 2; i++){
      ah[i] = *(const bf16x8*)&lsAh[cur][(wm*32 + i*16 + fr)*32 + kg*8];
      al[i] = *(const bf16x8*)&lsAl[cur][(wm*32 + i*16 + fr)*32 + kg*8];
    }
#pragma unroll
    for (int j = 0; j < 4; j++){
      bh[j] = *(const bf16x8*)&lsBh[cur][(wn*64 + j*16 + fr)*32 + kg*8];
      bl[j] = *(const bf16x8*)&lsBl[cur][(wn*64 + j*16 + fr)*32 + kg*8];
    }
#pragma unroll
    for (int mi = 0; mi < 2; mi++)
#pragma unroll
      for (int ni = 0; ni < 4; ni++){
        acc[mi][ni] = __builtin_amdgcn_mfma_f32_16x16x32_bf16(ah[mi], bh[ni], acc[mi][ni], 0, 0, 0);
        acc[mi][ni] = __builtin_amdgcn_mfma_f32_16x16x32_bf16(ah[mi], bl[ni], acc[mi][ni], 0, 0, 0);
        acc[mi][ni] = __builtin_amdgcn_mfma_f32_16x16x32_bf16(al[mi], bh[ni], acc[mi][ni], 0, 0, 0);
      }
    __syncthreads();            // drains prefetch + guards reuse of cur
    cur ^= 1;
  }

  const int r4 = (lane >> 4) * 4;
#pragma unroll
  for (int mi = 0; mi < 2; mi++){
#pragma unroll
    for (int ni = 0; ni < 4; ni++){
      const int col = n0 + wn*64 + ni*16 + fr;
      const float bb = BIAS ? bias[zin*biasStride + col] : 0.f;
#pragma unroll
      for (int r = 0; r < 4; r++){
        const int row = m0 + wm*32 + mi*16 + r4 + r;
        float v = acc[mi][ni][r] + bb;
        if (EPI == 0){
          u16 hv = f2bf(v), lv = f2bf(v - bf2f(hv));
          long idx = coff + (long)row*ldc + col;
          ((u16*)Cv)[idx] = hv;
          ((u16*)Cv)[idx + loOffC] = lv;
        } else if (EPI == 1){
          ((float*)Cv)[coff + (long)row*ldc + col] = v;
        } else if (EPI == 2){
          long idx = coff + (long)row*ldc + col;
          ((float*)Cv)[idx] = v + Res[idx];
        } else if (EPI == 3){
          u16 hv = f2bf(v), lv = f2bf(v - bf2f(hv));
          int b = row >> 10, q = row & 1023;
          int h = col >> 8, d = col & 255;
          long o = ((long)(b*NHc + h)*HDc + d)*2048 + q;
          ((u16*)Cv)[o] = hv;
          ((u16*)Cv)[o + 1024] = lv;
        } else {                      // EPI==4: merged QKV
          u16 hv = f2bf(v), lv = f2bf(v - bf2f(hv));
          if (z < 2){
            long idx = (long)z*sCin + (long)row*ldc + col;
            ((u16*)Cv)[idx] = hv;
            ((u16*)Cv)[idx + loOffC] = lv;
          } else {
            int b = row >> 10, q = row & 1023;
            int h = col >> 8, d = col & 255;
            long o = sCout + ((long)(b*NHc + h)*HDc + d)*2048 + q;
            ((u16*)Cv)[o] = hv;
            ((u16*)Cv)[o + 1024] = lv;
          }
        }
      }
    }
  }
}

// ---------------------------------------------------------------------------
// Plain bf16 NT GEMM, dbuf, 512 threads / 8 waves (4x2), acc[2][4].
template<int EPI, int SKIP, int SWZ>
__global__ __launch_bounds__(512)
void gemm_bt(const u16* __restrict__ A, const u16* __restrict__ B,
             void* __restrict__ Cv,
             int M, int N, int K, int lda, int ldb, int ldc,
             long sAz, long sBz, long sCz, const int* __restrict__ tc)
{
  __shared__ u16 lsA[2][128*32];
  __shared__ u16 lsB[2][128*32];
  int m_i, n_i;
  if (SWZ == 2){ m_i = blockIdx.x; n_i = blockIdx.y; }
  else         { n_i = blockIdx.x; m_i = blockIdx.y; }
  const int z = blockIdx.z;
  int n0 = n_i*128, m0 = m_i*128;
  if (SKIP == 3){ if ((m0 & 1023) >= tc[m0 >> 10]) return; }
  if (SKIP == 4){ if (!compact_m0(tc, m_i, m0)) return; }
  const u16* Ab = A + (long)z*sAz;
  const u16* Bb = B + (long)z*sBz;
  const int t = threadIdx.x, lane = t & 63;
  const int w = t >> 6;
  const int wm = w >> 1, wn = w & 1;
  const int fr = lane & 15, kg = lane >> 4;
  const int srow = t >> 2, scol = (t & 3) * 8;
  f32x4 acc[2][4] = {};

  auto stage = [&](int buf, int kb){
    gload_lds16(Ab + (long)(m0 + srow)*lda + kb + scol, &lsA[buf][srow*32 + scol]);
    gload_lds16(Bb + (long)(n0 + srow)*ldb + kb + scol, &lsB[buf][srow*32 + scol]);
  };

  stage(0, 0);
  __syncthreads();
  int cur = 0;
  for (int kb = 0; kb < K; kb += 32){
    if (kb + 32 < K) stage(cur ^ 1, kb + 32);
    bf16x8 av[2], bv[4];
#pragma unroll
    for (int i = 0; i < 2; i++)
      av[i] = *(const bf16x8*)&lsA[cur][(wm*32 + i*16 + fr)*32 + kg*8];
#pragma unroll
    for (int j = 0; j < 4; j++)
      bv[j] = *(const bf16x8*)&lsB[cur][(wn*64 + j*16 + fr)*32 + kg*8];
#pragma unroll
    for (int mi = 0; mi < 2; mi++)
#pragma unroll
      for (int ni = 0; ni < 4; ni++)
        acc[mi][ni] = __builtin_amdgcn_mfma_f32_16x16x32_bf16(av[mi], bv[ni], acc[mi][ni], 0, 0, 0);
    __syncthreads();
    cur ^= 1;
  }

  const int r4 = (lane >> 4) * 4;
#pragma unroll
  for (int mi = 0; mi < 2; mi++){
#pragma unroll
    for (int ni = 0; ni < 4; ni++){
      const int col = n0 + wn*64 + ni*16 + fr;
#pragma unroll
      for (int r = 0; r < 4; r++){
        const int row = m0 + wm*32 + mi*16 + r4 + r;
        const long idx = (long)z*sCz + (long)row*ldc + col;
        float v = acc[mi][ni][r];
        if      (EPI == 0) ((u16*)Cv)[idx]   = f2bf(v);
        else if (EPI == 1) ((float*)Cv)[idx] = v;
        else               ((float*)Cv)[idx] += v;
      }
    }
  }
}

// ---------------------------------------------------------------------------
// Gathered GU GEMM (double-buffered, 256 thr): per expert e, rows from sidx
__global__ __launch_bounds__(256)
void gemm_gu_gather(const u16* __restrict__ A, const u16* __restrict__ Ball,
                    u16* __restrict__ Cg, const int* __restrict__ sidx,
                    const int* __restrict__ counts, const int* __restrict__ offs)
{
  __shared__ u16 lsA[2][128*32];
  __shared__ u16 lsB[2][128*32];
  const int e = blockIdx.z;
  const int cnt = counts[e];
  const int obase = offs[e];
  const int padc = offs[e+1] - obase;
  const int m0 = blockIdx.y*128;
  if (m0 >= padc) return;
  const int n0 = blockIdx.x*128;
  const u16* B = Ball + (long)e*512*1024;
  const int t = threadIdx.x, lane = t & 63;
  const int w = t >> 6, wm = w >> 1, wn = w & 1;
  const int fr = lane & 15, kg = lane >> 4;
  const int srow = t >> 2, scol = (t & 3) * 8;
  const int s0 = m0 + srow, s1 = m0 + 64 + srow;
  const int tok0 = (s0 < cnt) ? sidx[e*NTOK + s0] : 0;
  const int tok1 = (s1 < cnt) ? sidx[e*NTOK + s1] : 0;
  f32x4 acc[4][4] = {};

  auto stage = [&](int buf, int kb){
    gload_lds16(A + (long)tok0*1024 + kb + scol, &lsA[buf][srow*32 + scol]);
    gload_lds16(A + (long)tok1*1024 + kb + scol, &lsA[buf][(64+srow)*32 + scol]);
    gload_lds16(B + (long)(n0 +      srow)*1024 + kb + scol, &lsB[buf][srow*32 + scol]);
    gload_lds16(B + (long)(n0 + 64 + srow)*1024 + kb + scol, &lsB[buf][(64+srow)*32 + scol]);
  };

  stage(0, 0);
  __syncthreads();
  int cur = 0;
  for (int kb = 0; kb < 1024; kb += 32){
    if (kb + 32 < 1024) stage(cur ^ 1, kb + 32);
    bf16x8 av[4], bv[4];
#pragma unroll
    for (int i = 0; i < 4; i++){
      av[i] = *(const bf16x8*)&lsA[cur][(wm*64 + i*16 + fr)*32 + kg*8];
      bv[i] = *(const bf16x8*)&lsB[cur][(wn*64 + i*16 + fr)*32 + kg*8];
    }
#pragma unroll
    for (int mi = 0; mi < 4; mi++)
#pragma unroll
      for (int ni = 0; ni < 4; ni++)
        acc[mi][ni] = __builtin_amdgcn_mfma_f32_16x16x32_bf16(av[mi], bv[ni], acc[mi][ni], 0, 0, 0);
    __syncthreads();
    cur ^= 1;
  }

  const int r4 = (lane >> 4) * 4;
#pragma unroll
  for (int mi = 0; mi < 4; mi++){
#pragma unroll
    for (int ni = 0; ni < 4; ni++){
      const int col = wn*64 + ni*16 + fr + n0;
#pragma unroll
      for (int r = 0; r < 4; r++){
        const int row = m0 + wm*64 + mi*16 + r4 + r;
        Cg[(long)(obase + row)*512 + col] = f2bf(acc[mi][ni][r]);
      }
    }
  }
}

// Down GEMM dense over slot space (double-buffered, 256 thr)
__global__ __launch_bounds__(256)
void gemm_down_slots(const u16* __restrict__ Zg, const u16* __restrict__ Wd,
                     u16* __restrict__ D, const int* __restrict__ offs)
{
  __shared__ u16 lsA[2][128*32];
  __shared__ u16 lsB[2][128*32];
  const int m0 = blockIdx.y*128;
  if (m0 >= offs[8]) return;
  int e = 0;
#pragma unroll
  for (int i = 0; i < 7; i++) if (m0 >= offs[i+1]) e = i+1;
  const u16* B = Wd + (long)e*1024*256;
  const int n0 = blockIdx.x*128;
  const int t = threadIdx.x, lane = t & 63;
  const int w = t >> 6, wm = w >> 1, wn = w & 1;
  const int fr = lane & 15, kg = lane >> 4;
  const int srow = t >> 2, scol = (t & 3) * 8;
  f32x4 acc[4][4] = {};

  auto stage = [&](int buf, int kb){
    gload_lds16(Zg + (long)(m0 +      srow)*256 + kb + scol, &lsA[buf][srow*32 + scol]);
    gload_lds16(Zg + (long)(m0 + 64 + srow)*256 + kb + scol, &lsA[buf][(64+srow)*32 + scol]);
    gload_lds16(B  + (long)(n0 +      srow)*256 + kb + scol, &lsB[buf][srow*32 + scol]);
    gload_lds16(B  + (long)(n0 + 64 + srow)*256 + kb + scol, &lsB[buf][(64+srow)*32 + scol]);
  };

  stage(0, 0);
  __syncthreads();
  int cur = 0;
  for (int kb = 0; kb < 256; kb += 32){
    if (kb + 32 < 256) stage(cur ^ 1, kb + 32);
    bf16x8 av[4], bv[4];
#pragma unroll
    for (int i = 0; i < 4; i++){
      av[i] = *(const bf16x8*)&lsA[cur][(wm*64 + i*16 + fr)*32 + kg*8];
      bv[i] = *(const bf16x8*)&lsB[cur][(wn*64 + i*16 + fr)*32 + kg*8];
    }
#pragma unroll
    for (int mi = 0; mi < 4; mi++)
#pragma unroll
      for (int ni = 0; ni < 4; ni++)
        acc[mi][ni] = __builtin_amdgcn_mfma_f32_16x16x32_bf16(av[mi], bv[ni], acc[mi][ni], 0, 0, 0);
    __syncthreads();
    cur ^= 1;
  }

  const int r4 = (lane >> 4) * 4;
#pragma unroll
  for (int mi = 0; mi < 4; mi++){
#pragma unroll
    for (int ni = 0; ni < 4; ni++){
      const int col = n0 + wn*64 + ni*16 + fr;
#pragma unroll
      for (int r = 0; r < 4; r++){
        const int row = m0 + wm*64 + mi*16 + r4 + r;
        D[(long)row*1024 + col] = f2bf(acc[mi][ni][r]);
      }
    }
  }
}

// ---------------------------------------------------------------------------
// FUSED weight prep: replaces 7 launches (Wqkv/Woutp splits, Wed/Wsg/Wsu/Wsd
// casts, expert-norm fold) with one grid-stride kernel; identical math.
__global__ void prep_all_k(const float* __restrict__ Wqkv, const float* __restrict__ Woutp,
                           const float* __restrict__ Wed, const float* __restrict__ Wsg,
                           const float* __restrict__ Wsu, const float* __restrict__ Wsd,
                           const float* __restrict__ Weg, const float* __restrict__ Weu,
                           const float* __restrict__ nw,
                           u16* __restrict__ qH, u16* __restrict__ qL,
                           u16* __restrict__ oH, u16* __restrict__ oL,
                           u16* __restrict__ wd, u16* __restrict__ sgu,
                           u16* __restrict__ sd, u16* __restrict__ gu){
  const long st = (long)gridDim.x*blockDim.x;
  const long i0 = (long)blockIdx.x*blockDim.x + threadIdx.x;
  const long nQ = 3145728, nO = 1048576, nD = 2097152, nS = 524288, nG = 2097152;
  for (long j = i0; j < nQ; j += st){
    float v = Wqkv[j]; u16 h = f2bf(v); qH[j] = h; qL[j] = f2bf(v - bf2f(h));
  }
  for (long j = i0; j < nO; j += st){
    float v = Woutp[j]; u16 h = f2bf(v); oH[j] = h; oL[j] = f2bf(v - bf2f(h));
  }
  for (long j = i0; j < nD; j += st) wd[j] = f2bf(Wed[j]);
  for (long j = i0; j < nS; j += st){
    sgu[j]      = f2bf(Wsg[j]);
    sgu[j + nS] = f2bf(Wsu[j]);
    sd[j]       = f2bf(Wsd[j]);
  }
  for (long j = i0; j < nG; j += st){
    int h  = (int)(j & (Hc - 1));
    int ii = (int)((j >> 10) & (Ic - 1));
    int e  = (int)(j >> 18);
    float wv = nw[e*Hc + h];
    long o = (long)e*(2*Ic*Hc) + (long)ii*Hc + h;
    gu[o]         = f2bf(Weg[j]*wv);
    gu[o + Ic*Hc] = f2bf(Weu[j]*wv);
  }
}

__global__ __launch_bounds__(256)
void rmsnorm_split_k(const float* __restrict__ x, const float* __restrict__ w1,
                     u16* __restrict__ o){
  const int row = blockIdx.x, t = threadIdx.x, lane = t & 63, w = t >> 6;
  float4 v = ((const float4*)(x + (long)row*Hc))[t];
  float ss = v.x*v.x + v.y*v.y + v.z*v.z + v.w*v.w;
  for (int off = 32; off; off >>= 1) ss += __shfl_xor(ss, off);
  __shared__ float red[4];
  if (lane == 0) red[w] = ss;
  __syncthreads();
  float rs = rsqrtf((red[0]+red[1]+red[2]+red[3])*(1.f/Hc) + EPSc);
  float4 wv = ((const float4*)w1)[t];
  float f0 = v.x*rs*wv.x, f1 = v.y*rs*wv.y, f2 = v.z*rs*wv.z, f3 = v.w*rs*wv.w;
  ushort4 hv, lv;
  hv.x = f2bf(f0); lv.x = f2bf(f0 - bf2f(hv.x));
  hv.y = f2bf(f1); lv.y = f2bf(f1 - bf2f(hv.y));
  hv.z = f2bf(f2); lv.z = f2bf(f2 - bf2f(hv.z));
  hv.w = f2bf(f3); lv.w = f2bf(f3 - bf2f(hv.w));
  u16* r16 = o + (long)row*2048;
  ((ushort4*)r16)[t] = hv;
  ((ushort4*)(r16 + 1024))[t] = lv;
}

// fused rmsnorm (xhat w=1, sx with shared_norm_w) + gating top-2 per token row
__global__ __launch_bounds__(256)
void norm_gate_k(const float* __restrict__ x, const float* __restrict__ shw,
                 const float* __restrict__ gnw, const float* __restrict__ gw,
                 const int* __restrict__ tcnt,
                 u16* __restrict__ xhat, u16* __restrict__ sx,
                 int* __restrict__ topi, float* __restrict__ topw){
  const int row = blockIdx.x, t = threadIdx.x, lane = t & 63, w = t >> 6;
  float4 v = ((const float4*)(x + (long)row*Hc))[t];
  float ss = v.x*v.x + v.y*v.y + v.z*v.z + v.w*v.w;
  for (int off = 32; off; off >>= 1) ss += __shfl_xor(ss, off);
  __shared__ float red[4];
  __shared__ float gred[4][8];
  if (lane == 0) red[w] = ss;
  __syncthreads();
  float rs = rsqrtf((red[0]+red[1]+red[2]+red[3])*(1.f/Hc) + EPSc);
  ushort4 ov;
  ov.x = f2bf(v.x*rs); ov.y = f2bf(v.y*rs); ov.z = f2bf(v.z*rs); ov.w = f2bf(v.w*rs);
  ((ushort4*)xhat)[(long)row*256 + t] = ov;
  float4 sv = ((const float4*)shw)[t];
  ov.x = f2bf(v.x*rs*sv.x); ov.y = f2bf(v.y*rs*sv.y);
  ov.z = f2bf(v.z*rs*sv.z); ov.w = f2bf(v.w*rs*sv.w);
  ((ushort4*)sx)[(long)row*256 + t] = ov;

  const int b = row >> 10, l = row & 1023;
  if (l >= tcnt[b]) return;
  float4 g = ((const float4*)gnw)[t];
  float xg0 = v.x*g.x, xg1 = v.y*g.y, xg2 = v.z*g.z, xg3 = v.w*g.w;
  float pe[8];
#pragma unroll
  for (int e = 0; e < 8; e++){
    float4 ww = ((const float4*)(gw + (long)e*Hc))[t];
    pe[e] = xg0*ww.x + xg1*ww.y + xg2*ww.z + xg3*ww.w;
  }
  for (int off = 32; off; off >>= 1){
#pragma unroll
    for (int e = 0; e < 8; e++) pe[e] += __shfl_xor(pe[e], off);
  }
  if (lane == 0){
#pragma unroll
    for (int e = 0; e < 8; e++) gred[w][e] = pe[e];
  }
  __syncthreads();
  if (t == 0){
    float sc[8], m = -3.4e38f;
#pragma unroll
    for (int e = 0; e < 8; e++){
      sc[e] = (gred[0][e]+gred[1][e]+gred[2][e]+gred[3][e])*rs;
      m = fmaxf(m, sc[e]);
    }
    float p[8], sum = 0.f;
#pragma unroll
    for (int e = 0; e < 8; e++){ p[e] = __expf(sc[e] - m); sum += p[e]; }
    float inv = 1.f/sum;
#pragma unroll
    for (int e = 0; e < 8; e++) p[e] *= inv;
    int i1 = 0; float v1 = p[0];
#pragma unroll
    for (int e = 1; e < 8; e++) if (p[e] > v1){ v1 = p[e]; i1 = e; }
    int i2 = -1; float v2 = -1.f;
#pragma unroll
    for (int e = 0; e < 8; e++) if (e != i1 && p[e] > v2){ v2 = p[e]; i2 = e; }
    float dn = v1 + v2 + 1e-20f;
    topi[2*row] = i1; topi[2*row + 1] = i2;
    topw[2*row] = v1/dn; topw[2*row + 1] = v2/dn;
  }
}

// masked softmax; skips padded q rows. b = bbase + ((rid>>10) & bmask)
__global__ __launch_bounds__(256)
void softmax2_k(float* __restrict__ S, const int* __restrict__ cnt, int bbase, int bmask){
  const int rid = blockIdx.x;
  const int b = bbase + ((rid >> 10) & bmask);
  const int n = cnt[b];
  if ((rid & 1023) >= n) return;
  float* row = S + (long)rid*Lc;
  const int t = threadIdx.x, lane = t & 63, w = t >> 6;
  float4 v = ((const float4*)row)[t];
  const float sc = 0.0625f;
  float vals[4] = {v.x*sc, v.y*sc, v.z*sc, v.w*sc};
  const int c = t*4;
  float m = -3.4e38f;
#pragma unroll
  for (int j = 0; j < 4; j++) if (c + j < n) m = fmaxf(m, vals[j]);
  for (int o = 32; o; o >>= 1) m = fmaxf(m, __shfl_xor(m, o));
  __shared__ float red[8];
  if (lane == 0) red[w] = m;
  __syncthreads();
  m = fmaxf(fmaxf(red[0], red[1]), fmaxf(red[2], red[3]));
  float p[4], s = 0.f;
#pragma unroll
  for (int j = 0; j < 4; j++){ p[j] = (c + j < n) ? __expf(vals[j] - m) : 0.f; s += p[j]; }
  for (int o = 32; o; o >>= 1) s += __shfl_xor(s, o);
  if (lane == 0) red[4 + w] = s;
  __syncthreads();
  const float inv = 1.f / (red[4]+red[5]+red[6]+red[7]);
  ushort4 hv, lv;
  float q0 = p[0]*inv, q1 = p[1]*inv, q2 = p[2]*inv, q3 = p[3]*inv;
  hv.x = f2bf(q0); lv.x = f2bf(q0 - bf2f(hv.x));
  hv.y = f2bf(q1); lv.y = f2bf(q1 - bf2f(hv.y));
  hv.z = f2bf(q2); lv.z = f2bf(q2 - bf2f(hv.z));
  hv.w = f2bf(q3); lv.w = f2bf(q3 - bf2f(hv.w));
  u16* r16 = (u16*)S + (long)rid*2048;
  ((ushort4*)r16)[t] = hv;
  ((ushort4*)(r16 + 1024))[t] = lv;
}

// deterministic routing build: single block, 1024 threads, token-ordered.
__global__ __launch_bounds__(1024)
void route_scan_k(const int* __restrict__ tcnt, const int* __restrict__ topi,
                  const float* __restrict__ topw, int* __restrict__ counts,
                  int* __restrict__ offs, int* __restrict__ sidx,
                  int* __restrict__ gpos, float* __restrict__ wG){
  __shared__ int hist[1024][8];
  __shared__ int soffs[9];
  const int t = threadIdx.x;
  for (int i = t; i < MAXSLOTS; i += 1024) wG[i] = 0.f;
  int h[8] = {0,0,0,0,0,0,0,0};
  const int n0 = t*8;
  int e0[8], e1[8];
#pragma unroll
  for (int k = 0; k < 8; k++){
    const int n = n0 + k;
    const int b = n >> 10, l = n & 1023;
    const bool val = l < tcnt[b];
    e0[k] = val ? topi[2*n]   : -1;
    e1[k] = val ? topi[2*n+1] : -1;
    if (val){ h[e0[k]]++; h[e1[k]]++; }
  }
#pragma unroll
  for (int e = 0; e < 8; e++) hist[t][e] = h[e];
  __syncthreads();
  for (int off = 1; off < 1024; off <<= 1){
    int v[8];
#pragma unroll
    for (int e = 0; e < 8; e++)
      v[e] = hist[t][e] + ((t >= off) ? hist[t - off][e] : 0);
    __syncthreads();
#pragma unroll
    for (int e = 0; e < 8; e++) hist[t][e] = v[e];
    __syncthreads();
  }
  if (t == 0){
    int o = 0; soffs[0] = 0; offs[0] = 0;
    for (int e = 0; e < 8; e++){
      int c = hist[1023][e];
      counts[e] = c;
      o += (c + 127) & ~127;
      soffs[e+1] = o;
      offs[e+1] = o;
    }
  }
  __syncthreads();
  int run[8];
#pragma unroll
  for (int e = 0; e < 8; e++) run[e] = hist[t][e] - h[e];
#pragma unroll
  for (int k = 0; k < 8; k++){
    const int n = n0 + k;
    if (e0[k] >= 0){
      const int p0 = run[e0[k]]++;
      const int p1 = run[e1[k]]++;
      sidx[e0[k]*NTOK + p0] = n;
      sidx[e1[k]*NTOK + p1] = n;
      const int g0 = soffs[e0[k]] + p0, g1 = soffs[e1[k]] + p1;
      gpos[2*n] = g0; gpos[2*n+1] = g1;
      wG[g0] = topw[2*n]; wG[g1] = topw[2*n+1];
    } else {
      gpos[2*n] = 0; gpos[2*n+1] = 0;
    }
  }
}

__global__ void act_shared_k(const u16* __restrict__ gu, u16* __restrict__ z, long n){
  long i = (long)blockIdx.x*blockDim.x + threadIdx.x;
  long st = (long)gridDim.x*blockDim.x;
  for (; i < n; i += st){
    long nn = i >> 9;
    int  ii = (int)(i & (ISc - 1));
    float gv = bf2f(gu[nn*1024 + ii]);
    float uv = bf2f(gu[nn*1024 + ISc + ii]);
    z[i] = f2bf(gv/(1.f + __expf(-gv)) * uv);
  }
}

__global__ void act_slots_k(const u16* __restrict__ gu, const float* __restrict__ wG,
                            const int* __restrict__ offs, u16* __restrict__ z){
  long nmax = (long)offs[8]*256;
  long st = (long)gridDim.x*blockDim.x;
  for (long i = (long)blockIdx.x*blockDim.x + threadIdx.x; i < nmax; i += st){
    long s = i >> 8;
    int ii = (int)(i & 255);
    float gv = bf2f(gu[s*512 + ii]);
    float uv = bf2f(gu[s*512 + 256 + ii]);
    z[i] = f2bf(gv/(1.f + __expf(-gv)) * uv * wG[s]);
  }
}

__global__ void act_expert_k(const u16* __restrict__ gu, const int* __restrict__ topi,
                             const float* __restrict__ topw, int e,
                             u16* __restrict__ z, long n){
  long i = (long)blockIdx.x*blockDim.x + threadIdx.x;
  long st = (long)gridDim.x*blockDim.x;
  for (; i < n; i += st){
    long nn = i >> 8;
    int  ii = (int)(i & (Ic - 1));
    float wv = 0.f;
    if      (topi[2*nn]     == e) wv = topw[2*nn];
    else if (topi[2*nn + 1] == e) wv = topw[2*nn + 1];
    float gv = bf2f(gu[nn*512 + ii]);
    float uv = bf2f(gu[nn*512 + Ic + ii]);
    z[i] = f2bf(gv/(1.f + __expf(-gv)) * uv * wv);
  }
}

__global__ __launch_bounds__(256)
void final2_k(const float* __restrict__ ysh, const u16* __restrict__ D,
              const int* __restrict__ gpos, const float* __restrict__ ogw,
              const float* __restrict__ ogb, const int* __restrict__ cnt,
              float* __restrict__ out){
  const int t = threadIdx.x, lane = t & 63, w = t >> 6;
  const int n = blockIdx.x*4 + w;
  const int b = n >> 10, l = n & 1023;
  float* outr = out + (long)n*Hc;
  if (l >= cnt[b]){
#pragma unroll
    for (int j = 0; j < 16; j++) outr[j*64 + lane] = 0.f;
    return;
  }
  const float* yr = ysh + (long)n*Hc;
  const u16* d0 = D + (long)gpos[2*n]*1024;
  const u16* d1 = D + (long)gpos[2*n+1]*1024;
  float dot = 0.f, yv[16];
#pragma unroll
  for (int j = 0; j < 16; j++){
    int d = j*64 + lane;
    yv[j] = yr[d] + bf2f(d0[d]) + bf2f(d1[d]);
    dot += yv[j]*ogw[d];
  }
  for (int o = 32; o; o >>= 1) dot += __shfl_xor(dot, o);
  float s = 1.f/(1.f + __expf(-(dot + ogb[0])));
#pragma unroll
  for (int j = 0; j < 16; j++) outr[j*64 + lane] = yv[j]*s;
}

__global__ __launch_bounds__(256)
void final_k(const float* __restrict__ y, const float* __restrict__ ogw,
             const float* __restrict__ ogb, const int* __restrict__ cnt,
             float* __restrict__ out){
  const int t = threadIdx.x, lane = t & 63, w = t >> 6;
  const int n = blockIdx.x*4 + w;
  const int b = n >> 10, l = n & 1023;
  const bool pad = l >= cnt[b];
  const float* yr = y + (long)n*Hc;
  float dot = 0.f, yv[16];
#pragma unroll
  for (int j = 0; j < 16; j++){
    int d = j*64 + lane;
    yv[j] = yr[d];
    dot += yv[j]*ogw[d];
  }
  for (int o = 32; o; o >>= 1) dot += __shfl_xor(dot, o);
  float s = 1.f/(1.f + __expf(-(dot + ogb[0])));
  float* outr = out + (long)n*Hc;
#pragma unroll
  for (int j = 0; j < 16; j++){
    int d = j*64 + lane;
    outr[d] = pad ? 0.f : yv[j]*s;
  }
}

__global__ void sentinel_k(float* out){ out[0] = 1.0e9f; }

// ---------------------------------------------------------------------------
extern "C" void kernel_launch(void* const* d_in, const int* in_sizes, int n_in,
                              void* d_out, int out_size, void* d_ws, size_t ws_size,
                              hipStream_t stream){
  const float* hidden  = (const float*)d_in[0];
  const int*   cnt     = (const int*)  d_in[1];
  const float* ctx_nw  = (const float*)d_in[2];
  const float* Wqkv    = (const float*)d_in[3];
  const float* in_b    = (const float*)d_in[4];
  const float* Woutp   = (const float*)d_in[5];
  const float* out_b   = (const float*)d_in[6];
  const float* gate_nw = (const float*)d_in[7];
  const float* gate_w  = (const float*)d_in[8];
  const float* exp_nw  = (const float*)d_in[9];
  const float* Weg     = (const float*)d_in[10];
  const float* Weu     = (const float*)d_in[11];
  const float* Wed     = (const float*)d_in[12];
  const float* sh_nw   = (const float*)d_in[13];
  const float* Wsg     = (const float*)d_in[14];
  const float* Wsu     = (const float*)d_in[15];
  const float* Wsd     = (const float*)d_in[16];
  const float* ogw     = (const float*)d_in[17];
  const float* ogb     = (const float*)d_in[18];
  float* out = (float*)d_out;

  const size_t MB = 1024*1024;
  char* ws = (char*)d_ws;
  size_t off = 0;
  auto alloc = [&](size_t bytes)->char*{
    char* p = ws + off; off += (bytes + 255) & ~(size_t)255; return p;
  };
  u16* wWqH  = (u16*)alloc((size_t)3072*1024*2);
  u16* wWqL  = (u16*)alloc((size_t)3072*1024*2);
  u16* wWoH  = (u16*)alloc((size_t)1024*1024*2);
  u16* wWoL  = (u16*)alloc((size_t)1024*1024*2);
  u16* wWgu  = (u16*)alloc((size_t)Ec*2*Ic*Hc*2);
  u16* wWd   = (u16*)alloc((size_t)Ec*Hc*Ic*2);
  u16* wWsgu = (u16*)alloc((size_t)2*ISc*Hc*2);
  u16* wWsd  = (u16*)alloc((size_t)Hc*ISc*2);
  int*   wTopI = (int*)  alloc((size_t)NTOK*2*4);
  float* wTopW = (float*)alloc((size_t)NTOK*2*4);
  int*   wGpos = (int*)  alloc((size_t)NTOK*2*4);
  int*   wSidx = (int*)  alloc((size_t)Ec*NTOK*4);
  float* wG    = (float*)alloc((size_t)MAXSLOTS*4);
  int*   wCnts = (int*)  alloc(64);
  int*   wOffs = (int*)  alloc(64);
  char* P1 = alloc(32*MB);
  char* P2 = alloc(32*MB);   // Qp
  char* P3 = alloc(32*MB);   // Kp  (= P2 + 32MB)
  char* P4 = alloc(32*MB);   // Vtp (= P2 + 64MB)
  size_t fixed = off;
  const int mode = (fixed + 128*MB <= ws_size) ? 2 :
                   (fixed + 64*MB  <= ws_size) ? 1 : 0;
  char* P5 = alloc(mode == 2 ? 128*MB : mode == 1 ? 64*MB : 16*MB);
  if (off > ws_size){ sentinel_k<<<1,1,0,stream>>>(out); return; }

  u16*   wNx   = (u16*)P1;
  u16*   wCtx  = (u16*)P1;
  float* wY    = (float*)P1;
  u16*   wQp   = (u16*)P2;
  u16*   wXhat = (u16*)P2;
  u16*   wSx   = (u16*)(P2 + 16*MB);
  u16*   wKp   = (u16*)P3;
  float* wX    = (float*)P3;
  u16*   wGUg  = (u16*)P3;
  u16*   wZg   = (u16*)(P3 + 18*MB);
  u16*   wGUe  = (u16*)P3;
  u16*   wZe   = (u16*)(P3 + 8*MB);
  u16*   wVtp  = (u16*)P4;
  u16*   wGUs  = (u16*)P4;
  u16*   wZs   = (u16*)(P4 + 16*MB);
  float* wS    = (float*)P5;
  u16*   wD    = (u16*)P5;

  // 1) fused weight prep (1 launch replaces 7)
  prep_all_k<<<2048, 256, 0, stream>>>(Wqkv, Woutp, Wed, Wsg, Wsu, Wsd,
                                       Weg, Weu, exp_nw,
                                       wWqH, wWqL, wWoH, wWoL, wWd,
                                       wWsgu, wWsd, wWgu);

  // 2) pre-attn norm + MERGED Q/K/V projection (compact-live grid, 512 thr)
  rmsnorm_split_k<<<NTOK, 256, 0, stream>>>(hidden, ctx_nw, wNx);
  gemm3<4, 1, 4, 2, 0><<<dim3(64, 8, 3), 512, 0, stream>>>(
      wNx, wNx + 1024, wWqH, wWqL, wQp, in_b, nullptr,
      NTOK, 1024, 1024, 2048, 1024, 2048,
      0, 0, (long)1024*1024, 0,
      (long)16*1024*1024,        // z stride Qp->Kp (u16)
      (long)32*1024*1024,        // V base offset from Qp (u16)
      1024, 1024, cnt, 0);

  // 3) attention
  if (mode == 2){
    gemm3<1, 0, 1, 1, 1><<<dim3(8, 8, 32), 512, 0, stream>>>(
        wQp, wQp + 1024, wKp, wKp + 1024, wS, nullptr, nullptr,
        Lc, Lc, HDc, 2048, 2048, Lc,
        (long)Lc*2048, (long)HDc,
        (long)Lc*2048, (long)HDc,
        (long)Lc*Lc,   (long)8*Lc*Lc,
        0, 0, cnt, 0);
    softmax2_k<<<32*1024, 256, 0, stream>>>(wS, cnt, 0, 7);
    gemm3<0, 0, 2, 1, 1><<<dim3(2, 8, 32), 512, 0, stream>>>(
        (const u16*)wS, (const u16*)wS + 1024, wVtp, wVtp + 1024, wCtx,
        nullptr, nullptr,
        Lc, HDc, Lc, 2048, 2048, 2048,
        (long)Lc*2048,      (long)8*Lc*2048,
        (long)NHc*HDc*2048, (long)HDc*2048,
        (long)Lc*2048,      (long)HDc,
        1024, 0, cnt, 0);
  } else if (mode == 1){
    for (int g = 0; g < 2; g++){
      const int bbase = g*4;
      const long tokoff = (long)g*4*Lc*2048;
      const u16* Qb = wQp + tokoff;
      const u16* Kb = wKp + tokoff;
      gemm3<1, 0, 1, 1, 0><<<dim3(8, 8, 16), 512, 0, stream>>>(
          Qb, Qb + 1024, Kb, Kb + 1024, wS, nullptr, nullptr,
          Lc, Lc, HDc, 2048, 2048, Lc,
          (long)Lc*2048, (long)HDc,
          (long)Lc*2048, (long)HDc,
          (long)Lc*Lc,   (long)4*Lc*Lc,
          0, 0, cnt, bbase);
      softmax2_k<<<16*1024, 256, 0, stream>>>(wS, cnt, bbase, 3);
      const u16* Vb = wVtp + (long)g*4*NHc*HDc*2048;
      u16* Cb = wCtx + tokoff;
      gemm3<0, 0, 2, 1, 0><<<dim3(2, 8, 16), 512, 0, stream>>>(
          (const u16*)wS, (const u16*)wS + 1024, Vb, Vb + 1024, Cb, nullptr, nullptr,
          Lc, HDc, Lc, 2048, 2048, 2048,
          (long)Lc*2048,     (long)4*Lc*2048,
          (long)NHc*HDc*2048,(long)HDc*2048,
          (long)Lc*2048,     (long)HDc,
          1024, 0, cnt, bbase);
    }
  } else {
    for (int g = 0; g < 8; g++){
      const int hf = g >> 2, hbase = g & 3, bbase = hf*4;
      const long tokoff = (long)hf*4*Lc*2048;
      const u16* Qb = wQp + tokoff + hbase*HDc;
      const u16* Kb = wKp + tokoff + hbase*HDc;
      gemm3<1, 0, 1, 0, 0><<<dim3(8, 8, 4), 512, 0, stream>>>(
          Qb, Qb + 1024, Kb, Kb + 1024, wS, nullptr, nullptr,
          Lc, Lc, HDc, 2048, 2048, Lc,
          (long)Lc*2048, (long)HDc,
          (long)Lc*2048, (long)HDc,
          (long)Lc*Lc,   (long)4*Lc*Lc,
          0, 0, cnt, bbase);
      softmax2_k<<<4*1024, 256, 0, stream>>>(wS, cnt, bbase, 3);
      const u16* Vb = wVtp + (long)hf*4*NHc*HDc*2048 + (long)hbase*HDc*2048;
      u16* Cb = wCtx + tokoff + hbase*HDc;
      gemm3<0, 0, 2, 0, 0><<<dim3(2, 8, 4), 512, 0, stream>>>(
          (const u16*)wS, (const u16*)wS + 1024, Vb, Vb + 1024, Cb, nullptr, nullptr,
          Lc, HDc, Lc, 2048, 2048, 2048,
          (long)Lc*2048,     (long)4*Lc*2048,
          (long)NHc*HDc*2048,(long)HDc*2048,
          (long)Lc*2048,     (long)HDc,
          1024, 0, cnt, bbase);
    }
  }

  // 4) out-proj + bias + residual -> X f32 (compact-live grid)
  gemm3<2, 1, 4, 2, 0><<<dim3(64, 8, 1), 512, 0, stream>>>(
      wCtx, wCtx + 1024, wWoH, wWoL, wX, out_b, hidden,
      NTOK, 1024, 1024, 2048, 1024, 1024,
      0, 0, 0, 0, 0, 0, 0, 0, cnt, 0);

  // 5) fused rmsnorm + gating, then deterministic route build
  norm_gate_k<<<NTOK, 256, 0, stream>>>(wX, sh_nw, gate_nw, gate_w, cnt,
                                        wXhat, wSx, wTopI, wTopW);
  route_scan_k<<<1, 1024, 0, stream>>>(cnt, wTopI, wTopW, wCnts, wOffs,
                                       wSidx, wGpos, wG);

  // 6) shared experts -> Y (compact-live grid, 512 thr)
  gemm_bt<0, 4, 2><<<dim3(64, 8, 1), 512, 0, stream>>>(
      wSx, wWsgu, wGUs, NTOK, 2*ISc, 1024, 1024, 1024, 2*ISc, 0, 0, 0, cnt);
  act_shared_k<<<4096, 256, 0, stream>>>(wGUs, wZs, (long)NTOK*ISc);
  gemm_bt<1, 4, 2><<<dim3(64, 8, 1), 512, 0, stream>>>(
      wZs, wWsd, wY, NTOK, 1024, ISc, ISc, ISc, 1024, 0, 0, 0, cnt);

  // 7) routed experts
  if (mode >= 1){
    gemm_gu_gather<<<dim3(4, 64, Ec), 256, 0, stream>>>(
        wXhat, wWgu, wGUg, wSidx, wCnts, wOffs);
    act_slots_k<<<2048, 256, 0, stream>>>(wGUg, wG, wOffs, wZg);
    gemm_down_slots<<<dim3(8, MAXSLOTS/128, 1), 256, 0, stream>>>(
        wZg, wWd, wD, wOffs);
    final2_k<<<NTOK/4, 256, 0, stream>>>(wY, wD, wGpos, ogw, ogb, cnt, out);
  } else {
    for (int e = 0; e < Ec; e++){
      gemm_bt<0, 0, 0><<<dim3(4, 64, 1), 512, 0, stream>>>(
          wXhat, wWgu + (long)e*2*Ic*Hc, wGUe, NTOK, 2*Ic, 1024, 1024, 1024, 2*Ic,
          0, 0, 0, nullptr);
      act_expert_k<<<2048, 256, 0, stream>>>(wGUe, wTopI, wTopW, e, wZe, (long)NTOK*Ic);
      gemm_bt<2, 0, 0><<<dim3(8, 64, 1), 512, 0, stream>>>(
          wZe, wWd + (long)e*Hc*Ic, wY, NTOK, 1024, Ic, Ic, Ic, 1024, 0, 0, 0, nullptr);
    }
    final_k<<<NTOK/4, 256, 0, stream>>>(wY, ogw, ogb, cnt, out);
  }
}